// Round 14
// baseline (208.198 us; speedup 1.0000x reference)
//
#include <hip/hip_runtime.h>

#define NH   12
#define ND   64
#define NHD  768   // NH*ND
#define NSEQ 4096
#define NIT  16
#define MM   256   // rows per chunk
#define NBH  192
#define GRID1 512  // persistent K1 blocks: exactly 2/CU on 256 CUs

// LDS pitches (bf16 elems) — proven <=2-way classes (stride ≡ 4 mod 32 dwords)
#define T_P  264
#define W_P  72
#define G_P  72

typedef __bf16 bf16_t;
typedef bf16_t bf16x8 __attribute__((ext_vector_type(8)));
typedef float  f32x4  __attribute__((ext_vector_type(4)));

static __device__ __forceinline__ unsigned short f2bf(float f) {
    union { __bf16 h; unsigned short u; } v; v.h = (__bf16)f; return v.u;
}
static __device__ __forceinline__ float bf2f(unsigned short u) {
    union { unsigned u32; float f; } v; v.u32 = ((unsigned)u) << 16; return v.f;
}
static __device__ __forceinline__ bf16x8 pack8(float4 a, float4 b) {
    union { unsigned short u[8]; bf16x8 v; } r;
    r.u[0] = f2bf(a.x); r.u[1] = f2bf(a.y); r.u[2] = f2bf(a.z); r.u[3] = f2bf(a.w);
    r.u[4] = f2bf(b.x); r.u[5] = f2bf(b.y); r.u[6] = f2bf(b.z); r.u[7] = f2bf(b.w);
    return r.v;
}
static __device__ __forceinline__ void barrier_lds() {
    asm volatile("s_waitcnt lgkmcnt(0)" ::: "memory");
    __builtin_amdgcn_s_barrier();
    asm volatile("" ::: "memory");
}

// ============ Kernel 1: G_t = X^T X, H_t = X^T Y — persistent streaming ============
// 512 blocks x 256 thr: exactly 2 blocks/CU resident for the whole kernel (no
// scheduling rounds). Each block pipelines 6 chunks: X(next) loads fly across
// the compute barrier; per-tile G/H stores keep acc pressure at 8 regs.
extern "C" __global__ void __launch_bounds__(256)
ttt_gh(const float* __restrict__ kg, const float* __restrict__ vg,
       unsigned short* __restrict__ Gws, unsigned short* __restrict__ Hws)
{
    __shared__ unsigned short XT[64 * T_P] __attribute__((aligned(16)));
    __shared__ unsigned short YT[64 * T_P] __attribute__((aligned(16)));

    const int tid  = threadIdx.x;
    const int wv   = tid >> 6;      // 0..3
    const int lane = tid & 63;
    const int g    = lane >> 4;
    const int ln   = lane & 15;

    // staging ownership (R12-proven): rows {sr,sr+1,128+sr,129+sr}, cols c0..c0+15
    const int sr = (tid & 63) << 1;
    const int c0 = (tid >> 6) << 4;
    const int d0 = wv << 4;         // wave's d-tile

    const int TOT = NBH * NIT;      // 3072 tasks
    int task = blockIdx.x;

    // ---- prologue: stage chunk(task) X then Y (one exposed latency at start)
    {
        const float* xb = kg + (size_t)task * MM * ND;   // chunk base: bh*NSEQ+t*MM = task*MM
        float4 xr[16];
        const float* p0 = xb + (size_t)sr * ND + c0;
        const float* p1 = xb + (size_t)(128 + sr) * ND + c0;
        #pragma unroll
        for (int i = 0; i < 4; ++i) {
            xr[i]      = *(const float4*)(p0 + 4 * i);
            xr[4 + i]  = *(const float4*)(p0 + ND + 4 * i);
            xr[8 + i]  = *(const float4*)(p1 + 4 * i);
            xr[12 + i] = *(const float4*)(p1 + ND + 4 * i);
        }
        #pragma unroll
        for (int half = 0; half < 2; ++half) {
            const int m0 = half * 128 + sr;
            #pragma unroll
            for (int j = 0; j < 16; ++j) {
                float lo = ((const float*)&xr[half * 8 + (j >> 2)])[j & 3];
                float hi = ((const float*)&xr[half * 8 + 4 + (j >> 2)])[j & 3];
                *(unsigned*)&XT[(c0 + j) * T_P + m0] =
                    (unsigned)f2bf(lo) | ((unsigned)f2bf(hi) << 16);
            }
        }
        const float* yb = vg + (size_t)task * MM * ND;
        float4 yr[16];
        const float* q0 = yb + (size_t)sr * ND + c0;
        const float* q1 = yb + (size_t)(128 + sr) * ND + c0;
        #pragma unroll
        for (int i = 0; i < 4; ++i) {
            yr[i]      = *(const float4*)(q0 + 4 * i);
            yr[4 + i]  = *(const float4*)(q0 + ND + 4 * i);
            yr[8 + i]  = *(const float4*)(q1 + 4 * i);
            yr[12 + i] = *(const float4*)(q1 + ND + 4 * i);
        }
        #pragma unroll
        for (int half = 0; half < 2; ++half) {
            const int m0 = half * 128 + sr;
            #pragma unroll
            for (int j = 0; j < 16; ++j) {
                float lo = ((const float*)&yr[half * 8 + (j >> 2)])[j & 3];
                float hi = ((const float*)&yr[half * 8 + 4 + (j >> 2)])[j & 3];
                *(unsigned*)&YT[(c0 + j) * T_P + m0] =
                    (unsigned)f2bf(lo) | ((unsigned)f2bf(hi) << 16);
            }
        }
    }
    barrier_lds();

    for (;;) {
        const int nxt = task + (int)gridDim.x;
        const bool has = nxt < TOT;

        // issue X(nxt) loads: in flight across the whole compute phase
        float4 xr[16];
        if (has) {
            const float* xb = kg + (size_t)nxt * MM * ND;
            const float* p0 = xb + (size_t)sr * ND + c0;
            const float* p1 = xb + (size_t)(128 + sr) * ND + c0;
            #pragma unroll
            for (int i = 0; i < 4; ++i) {
                xr[i]      = *(const float4*)(p0 + 4 * i);
                xr[4 + i]  = *(const float4*)(p0 + ND + 4 * i);
                xr[8 + i]  = *(const float4*)(p1 + 4 * i);
                xr[12 + i] = *(const float4*)(p1 + ND + 4 * i);
            }
        }

        // ---- compute G/H(task): per-tile store keeps acc live = 8 regs
        {
            bf16x8 xa[8];
            #pragma unroll
            for (int kx = 0; kx < 8; ++kx)
                xa[kx] = *(const bf16x8*)&XT[(d0 + ln) * T_P + kx * 32 + g * 8];

            unsigned short* gout = Gws + (size_t)task * 4096;
            unsigned short* hout = Hws + (size_t)task * 4096;
            #pragma unroll
            for (int et = 0; et < 4; ++et) {
                const int e0 = et << 4;
                f32x4 ga = {0.f, 0.f, 0.f, 0.f};
                #pragma unroll
                for (int kx = 0; kx < 8; ++kx) {
                    bf16x8 bg = *(const bf16x8*)&XT[(e0 + ln) * T_P + kx * 32 + g * 8];
                    ga = __builtin_amdgcn_mfma_f32_16x16x32_bf16(xa[kx], bg, ga, 0, 0, 0);
                }
                #pragma unroll
                for (int j = 0; j < 4; ++j)
                    gout[(size_t)(d0 + 4 * g + j) * 64 + e0 + ln] = f2bf(ga[j]);
                f32x4 ha = {0.f, 0.f, 0.f, 0.f};
                #pragma unroll
                for (int kx = 0; kx < 8; ++kx) {
                    bf16x8 bh_ = *(const bf16x8*)&YT[(e0 + ln) * T_P + kx * 32 + g * 8];
                    ha = __builtin_amdgcn_mfma_f32_16x16x32_bf16(xa[kx], bh_, ha, 0, 0, 0);
                }
                #pragma unroll
                for (int j = 0; j < 4; ++j)
                    hout[(size_t)(d0 + 4 * g + j) * 64 + e0 + ln] = f2bf(ha[j]);
            }
        }

        if (!has) break;
        barrier_lds();   // all waves done reading XT/YT -> safe to overwrite

        // stage X(nxt) from xr (already landed or nearly), then Y(nxt)
        #pragma unroll
        for (int half = 0; half < 2; ++half) {
            const int m0 = half * 128 + sr;
            #pragma unroll
            for (int j = 0; j < 16; ++j) {
                float lo = ((const float*)&xr[half * 8 + (j >> 2)])[j & 3];
                float hi = ((const float*)&xr[half * 8 + 4 + (j >> 2)])[j & 3];
                *(unsigned*)&XT[(c0 + j) * T_P + m0] =
                    (unsigned)f2bf(lo) | ((unsigned)f2bf(hi) << 16);
            }
        }
        {
            const float* yb = vg + (size_t)nxt * MM * ND;
            float4 yr[16];
            const float* q0 = yb + (size_t)sr * ND + c0;
            const float* q1 = yb + (size_t)(128 + sr) * ND + c0;
            #pragma unroll
            for (int i = 0; i < 4; ++i) {
                yr[i]      = *(const float4*)(q0 + 4 * i);
                yr[4 + i]  = *(const float4*)(q0 + ND + 4 * i);
                yr[8 + i]  = *(const float4*)(q1 + 4 * i);
                yr[12 + i] = *(const float4*)(q1 + ND + 4 * i);
            }
            #pragma unroll
            for (int half = 0; half < 2; ++half) {
                const int m0 = half * 128 + sr;
                #pragma unroll
                for (int j = 0; j < 16; ++j) {
                    float lo = ((const float*)&yr[half * 8 + (j >> 2)])[j & 3];
                    float hi = ((const float*)&yr[half * 8 + 4 + (j >> 2)])[j & 3];
                    *(unsigned*)&YT[(c0 + j) * T_P + m0] =
                        (unsigned)f2bf(lo) | ((unsigned)f2bf(hi) << 16);
                }
            }
        }
        barrier_lds();   // XT/YT(nxt) ready
        task = nxt;
    }
}

// ============ Kernel 2: tiny scan + out GEMM (R12/R13-proven, unchanged) ============
extern "C" __global__ void __launch_bounds__(512)
ttt_scan(const float* __restrict__ qg, const unsigned short* __restrict__ Gws,
         const unsigned short* __restrict__ Hws, const float* __restrict__ Wi,
         float* __restrict__ outg)
{
    __shared__ unsigned short Gs[2][64 * G_P] __attribute__((aligned(16)));
    __shared__ unsigned short Hs[2][64 * G_P] __attribute__((aligned(16)));
    __shared__ unsigned short WB[2][64 * W_P] __attribute__((aligned(16)));

    const int tid  = threadIdx.x;
    const int wv   = tid >> 6;       // 0..7
    const int lane = tid & 63;
    const int g    = lane >> 4;
    const int ln   = lane & 15;

    const int bh = blockIdx.x;
    const int b  = bh / NH;
    const int h  = bh - b * NH;

    const float* qb = qg + (size_t)bh * NSEQ * ND;
    float* ob = outg + (size_t)b * NSEQ * NHD + h * ND;
    const unsigned short* gbase = Gws + (size_t)bh * NIT * 4096;
    const unsigned short* hbase = Hws + (size_t)bh * NIT * 4096;

    const int du = (wv & 3) << 4;
    const int eu = (wv >> 2) << 5;
    const int rc = wv << 5;
    const float s = 1.0f / 16384.0f;

    const int gr = tid >> 3;
    const int gc = (tid & 7) << 3;

    float wf[8];
    {
        const float* wp = Wi + (size_t)h * ND * ND;
        #pragma unroll
        for (int t2 = 0; t2 < 2; ++t2) {
            ushort4 wq; unsigned short* wqp = (unsigned short*)&wq;
            #pragma unroll
            for (int j = 0; j < 4; ++j) {
                wf[t2 * 4 + j] = wp[(size_t)(du + 4 * g + j) * ND + eu + t2 * 16 + ln];
                wqp[j] = f2bf(wf[t2 * 4 + j]);
            }
            *(ushort4*)&WB[0][(eu + t2 * 16 + ln) * W_P + du + 4 * g] = wq;
        }
    }
    {
        uint4 g0 = *(const uint4*)(gbase + (size_t)gr * 64 + gc);
        uint4 h0 = *(const uint4*)(hbase + (size_t)gr * 64 + gc);
        *(uint4*)&Gs[0][gr * G_P + gc] = g0;
        *(uint4*)&Hs[0][gr * G_P + gc] = h0;
    }
    uint4 greg, hreg;
    greg = *(const uint4*)(gbase + 4096 + (size_t)gr * 64 + gc);
    hreg = *(const uint4*)(hbase + 4096 + (size_t)gr * 64 + gc);
    float4 qr[8];
    barrier_lds();

    int cur = 0;
    for (int t = 0; t < NIT; ++t) {
        const int nxt = cur ^ 1;

        if (t + 1 < NIT) {
            *(uint4*)&Gs[nxt][gr * G_P + gc] = greg;
            *(uint4*)&Hs[nxt][gr * G_P + gc] = hreg;
        }
        if (t + 2 < NIT) {
            greg = *(const uint4*)(gbase + (size_t)(t + 2) * 4096 + (size_t)gr * 64 + gc);
            hreg = *(const uint4*)(hbase + (size_t)(t + 2) * 4096 + (size_t)gr * 64 + gc);
        }

        #pragma unroll
        for (int t2 = 0; t2 < 2; ++t2) {
            f32x4 ga = {0.f, 0.f, 0.f, 0.f};
            #pragma unroll
            for (int kx = 0; kx < 2; ++kx) {
                bf16x8 ag = *(const bf16x8*)&Gs[cur][(du + ln) * G_P + kx * 32 + g * 8];
                bf16x8 bw = *(const bf16x8*)&WB[cur][(eu + t2 * 16 + ln) * W_P + kx * 32 + g * 8];
                ga = __builtin_amdgcn_mfma_f32_16x16x32_bf16(ag, bw, ga, 0, 0, 0);
            }
            ushort4 wq; unsigned short* wqp = (unsigned short*)&wq;
            #pragma unroll
            for (int j = 0; j < 4; ++j) {
                float hv = bf2f(Hs[cur][(du + 4 * g + j) * G_P + eu + t2 * 16 + ln]);
                wf[t2 * 4 + j] -= s * (ga[j] - hv);
                wqp[j] = f2bf(wf[t2 * 4 + j]);
            }
            *(ushort4*)&WB[nxt][(eu + t2 * 16 + ln) * W_P + du + 4 * g] = wq;
        }

        if (t > 0) {
            #pragma unroll
            for (int ms = 0; ms < 2; ++ms) {
                bf16x8 aq0 = pack8(qr[ms * 4 + 0], qr[ms * 4 + 1]);
                bf16x8 aq1 = pack8(qr[ms * 4 + 2], qr[ms * 4 + 3]);
                #pragma unroll
                for (int et = 0; et < 4; ++et) {
                    bf16x8 w0 = *(const bf16x8*)&WB[cur][(et * 16 + ln) * W_P + g * 8];
                    bf16x8 w1 = *(const bf16x8*)&WB[cur][(et * 16 + ln) * W_P + 32 + g * 8];
                    f32x4 oc = {0.f, 0.f, 0.f, 0.f};
                    oc = __builtin_amdgcn_mfma_f32_16x16x32_bf16(aq0, w0, oc, 0, 0, 0);
                    oc = __builtin_amdgcn_mfma_f32_16x16x32_bf16(aq1, w1, oc, 0, 0, 0);
                    #pragma unroll
                    for (int j = 0; j < 4; ++j)
                        ob[((size_t)((t - 1) * MM) + rc + ms * 16 + 4 * g + j) * NHD + et * 16 + ln] = oc[j];
                }
            }
        }

        #pragma unroll
        for (int ms = 0; ms < 2; ++ms) {
            const float* qp = qb + ((size_t)(t * MM) + rc + ms * 16 + ln) * ND;
            qr[ms * 4 + 0] = *(const float4*)(qp + g * 8);
            qr[ms * 4 + 1] = *(const float4*)(qp + g * 8 + 4);
            qr[ms * 4 + 2] = *(const float4*)(qp + 32 + g * 8);
            qr[ms * 4 + 3] = *(const float4*)(qp + 32 + g * 8 + 4);
        }

        barrier_lds();
        cur ^= 1;
    }

    #pragma unroll
    for (int ms = 0; ms < 2; ++ms) {
        bf16x8 aq0 = pack8(qr[ms * 4 + 0], qr[ms * 4 + 1]);
        bf16x8 aq1 = pack8(qr[ms * 4 + 2], qr[ms * 4 + 3]);
        #pragma unroll
        for (int et = 0; et < 4; ++et) {
            bf16x8 w0 = *(const bf16x8*)&WB[cur][(et * 16 + ln) * W_P + g * 8];
            bf16x8 w1 = *(const bf16x8*)&WB[cur][(et * 16 + ln) * W_P + 32 + g * 8];
            f32x4 oc = {0.f, 0.f, 0.f, 0.f};
            oc = __builtin_amdgcn_mfma_f32_16x16x32_bf16(aq0, w0, oc, 0, 0, 0);
            oc = __builtin_amdgcn_mfma_f32_16x16x32_bf16(aq1, w1, oc, 0, 0, 0);
            #pragma unroll
            for (int j = 0; j < 4; ++j)
                ob[((size_t)(15 * MM) + rc + ms * 16 + 4 * g + j) * NHD + et * 16 + ln] = oc[j];
        }
    }
}

extern "C" void kernel_launch(void* const* d_in, const int* in_sizes, int n_in,
                              void* d_out, int out_size, void* d_ws, size_t ws_size,
                              hipStream_t stream) {
    const float* q  = (const float*)d_in[0];
    const float* k  = (const float*)d_in[1];
    const float* v  = (const float*)d_in[2];
    const float* Wi = (const float*)d_in[3];
    float* out = (float*)d_out;

    int nbh = in_sizes[0] / (NSEQ * ND);   // 192
    unsigned short* Gws = (unsigned short*)d_ws;
    unsigned short* Hws = Gws + (size_t)nbh * NIT * 4096;

    hipLaunchKernelGGL(ttt_gh, dim3(GRID1), dim3(256), 0, stream, k, v, Gws, Hws);
    hipLaunchKernelGGL(ttt_scan, dim3(nbh), dim3(512), 0, stream, q, Gws, Hws, Wi, out);
}